// Round 3
// baseline (917.646 us; speedup 1.0000x reference)
//
#include <hip/hip_runtime.h>

#define N_DIM 128   // NODE_DIM
#define L_DIM 64    // EDGE_LBL_DIM
#define F_DIM 128   // EDGE_FT_OUT_DIM
#define NREP 8      // one den replica per XCD (MI355X: 8 XCDs)

// hardware XCD id (wave-uniform). Symbolic hwreg name -> assembler guarantees encoding.
__device__ __forceinline__ int xcc_id() {
    int x;
    asm volatile("s_getreg_b32 %0, hwreg(HW_REG_XCC_ID)" : "=s"(x));
    return x & (NREP - 1);
}

// u[n] = h[n] . W_attn[128:256]  (one wave per node, grid-stride)
// block 0 threads 0..63 additionally compute v[k] = sum_f Wfc[k][f]*Wattn[f]
__global__ void k_u(const float* __restrict__ h,
                    const float* __restrict__ Wfc,
                    const float* __restrict__ Wattn,
                    float* __restrict__ u,
                    float* __restrict__ v, int N) {
    if (blockIdx.x == 0 && threadIdx.x < 64) {
        int k = threadIdx.x;
        float acc = 0.f;
#pragma unroll 8
        for (int f = 0; f < F_DIM; ++f) acc += Wfc[k * F_DIM + f] * Wattn[f];
        v[k] = acc;
    }
    int lane = threadIdx.x & 63;
    int wid = (int)((blockIdx.x * (unsigned)blockDim.x + threadIdx.x) >> 6);
    int nw  = (int)((gridDim.x * (unsigned)blockDim.x) >> 6);
    float2 wa = *(const float2*)(Wattn + F_DIM + 2 * lane);
    for (int n = wid; n < N; n += nw) {
        float2 hv = *(const float2*)(h + (long)n * N_DIM + 2 * lane);
        float p = hv.x * wa.x + hv.y * wa.y;
#pragma unroll
        for (int off = 32; off > 0; off >>= 1) p += __shfl_xor(p, off, 64);
        if (lane == 0) u[n] = p;
    }
}

// Fused logits+exp+den: ex[e] = exp(leaky_relu(el[e].v + u[src[e]]))
// den accumulated into per-XCD replica with WORKGROUP-scope atomics:
// -> global_atomic_add performed in the LOCAL TCC (L2), bypassing the
//    cross-XCD coherent path. All updaters of replica r are on XCD r.
__global__ void __launch_bounds__(256) k_se(const float* __restrict__ el,
                                            const float* __restrict__ v,
                                            const float* __restrict__ u,
                                            const int* __restrict__ src,
                                            float* __restrict__ ex_out,
                                            float* __restrict__ den_rep,
                                            int E, int N) {
    const int lane = threadIdx.x & 63;
    const int j16  = lane & 15;   // position within 16-lane group
    const int grp  = lane >> 4;   // group 0..3
    int wid = (int)((blockIdx.x * (unsigned)blockDim.x + threadIdx.x) >> 6);
    int nw  = (int)((gridDim.x * (unsigned)blockDim.x) >> 6);

    float* myrep = den_rep + (size_t)xcc_id() * N;

    float4 v4 = *(const float4*)(v + 4 * j16);  // v[k] slice for this lane's k-range
    const int C = (E + 63) >> 6;                // 64-edge chunks

    for (int c = wid; c < C; c += nw) {
        const long e0 = (long)c * 64;
        const int my_e = (int)e0 + 4 * j16 + grp;  // edge this lane retains
        const bool full = (e0 + 64 <= E);

        if (full) {
            int   sv = src[my_e];
            float uu = u[sv];
            float kept = 0.f;
            const float4* elv = (const float4*)(el + e0 * L_DIM);
#pragma unroll
            for (int j = 0; j < 16; ++j) {
                // edges 4j..4j+3: lane covers el[4j+grp][4*j16 .. 4*j16+3]
                float4 q = elv[j * 64 + lane];
                float p = q.x * v4.x + q.y * v4.y + q.z * v4.z + q.w * v4.w;
                p += __shfl_xor(p, 1, 64);
                p += __shfl_xor(p, 2, 64);
                p += __shfl_xor(p, 4, 64);
                p += __shfl_xor(p, 8, 64);
                // u of edge (4j+grp) is held by lane (16*grp + j)
                float ue = __shfl(uu, (grp << 4) | j, 64);
                float s  = p + ue;
                float ev = fmaxf(s, 0.01f * s);     // leaky_relu
                float exv = __expf(ev);
                kept = (j16 == j) ? exv : kept;
            }
            ex_out[my_e] = kept;  // permuted within 256B: coalesced
            __hip_atomic_fetch_add(myrep + sv, kept, __ATOMIC_RELAXED,
                                   __HIP_MEMORY_SCOPE_WORKGROUP);
        } else {
            for (int j = 0; j < 16; ++j) {  // tail (unused at E=800000)
                long e = e0 + 4 * j + grp;
                if (e >= E) continue;
                const float4* row = (const float4*)(el + e * L_DIM);
                float4 q = row[j16];
                float p = q.x * v4.x + q.y * v4.y + q.z * v4.z + q.w * v4.w;
                p += __shfl_xor(p, 1, 64);
                p += __shfl_xor(p, 2, 64);
                p += __shfl_xor(p, 4, 64);
                p += __shfl_xor(p, 8, 64);
                if (j16 == 0) {
                    int sv2 = src[e];
                    float s = p + u[sv2];
                    float ev = fmaxf(s, 0.01f * s);
                    float exv = __expf(ev);
                    ex_out[e] = exv;
                    __hip_atomic_fetch_add(myrep + sv2, exv, __ATOMIC_RELAXED,
                                           __HIP_MEMORY_SCOPE_WORKGROUP);
                }
            }
        }
    }
}

// den[n] = sum over the 8 XCD replicas
__global__ void k_merge(const float* __restrict__ rep,
                        float* __restrict__ den, int N) {
    int i = (int)(blockIdx.x * (unsigned)blockDim.x + threadIdx.x);
    if (i >= N) return;
    float s = 0.f;
#pragma unroll
    for (int r = 0; r < NREP; ++r) s += rep[(size_t)r * N + i];
    den[i] = s;
}

// out[e][f] = (ex[e]/den[src[e]]) * (el[e] . Wfc[:,f])
// One WAVE per 4-edge group. el block staged to a per-wave LDS slice
// (double-buffered); broadcast ds_read_b128 feeds the FMAs -> the 256
// v_readlane/group are moved off the VALU pipe onto the DS pipe.
__global__ void __launch_bounds__(256) k_out(const float* __restrict__ el,
                                             const float* __restrict__ Wfc,
                                             const int* __restrict__ src,
                                             const float* __restrict__ ex,
                                             const float* __restrict__ den,
                                             float* __restrict__ out,
                                             int E) {
    __shared__ float4 sle[2][4][4][16];  // [buf][wave][edge][k4] = 8 KB
    const int lane = threadIdx.x & 63;
    const int w    = threadIdx.x >> 6;
    const int gw = (int)(blockIdx.x * 4u + w);   // global wave id
    const int nw = (int)(gridDim.x * 4u);        // total waves
    const int G = E >> 2;                        // groups of 4 edges

    // Wfc columns 2*lane and 2*lane+1 into registers (coalesced float2 loads)
    float w0[L_DIM], w1[L_DIM];
#pragma unroll
    for (int k = 0; k < L_DIM; ++k) {
        float2 wv = *(const float2*)(Wfc + k * F_DIM + 2 * lane);
        w0[k] = wv.x;
        w1[k] = wv.y;
    }

    int g = gw;
    if (g >= G) return;

    float4 q = *(const float4*)(el + (long)g * (4 * L_DIM) + lane * 4);
    int buf = 0;
    sle[buf][w][lane >> 4][lane & 15] = q;

    while (true) {
        const int gn = g + nw;
        const bool more = gn < G;
        float4 qn;
        if (more) {  // prefetch next el block; stage into other LDS buffer
            qn = *(const float4*)(el + (long)gn * (4 * L_DIM) + lane * 4);
        }
        // per-group scalars: latency hides under the FMA block below
        float4 x4 = *(const float4*)(ex + 4 * (long)g);
        int4   s4 = *(const int4*)(src + 4 * (long)g);

        float a00 = 0.f, a01 = 0.f, a10 = 0.f, a11 = 0.f;
        float a20 = 0.f, a21 = 0.f, a30 = 0.f, a31 = 0.f;
#pragma unroll
        for (int k4 = 0; k4 < 16; ++k4) {
            float4 b0 = sle[buf][w][0][k4];  // broadcast reads (uniform addr)
            float4 b1 = sle[buf][w][1][k4];
            float4 b2 = sle[buf][w][2][k4];
            float4 b3 = sle[buf][w][3][k4];
            const int k = 4 * k4;
            a00 += b0.x * w0[k] + b0.y * w0[k+1] + b0.z * w0[k+2] + b0.w * w0[k+3];
            a01 += b0.x * w1[k] + b0.y * w1[k+1] + b0.z * w1[k+2] + b0.w * w1[k+3];
            a10 += b1.x * w0[k] + b1.y * w0[k+1] + b1.z * w0[k+2] + b1.w * w0[k+3];
            a11 += b1.x * w1[k] + b1.y * w1[k+1] + b1.z * w1[k+2] + b1.w * w1[k+3];
            a20 += b2.x * w0[k] + b2.y * w0[k+1] + b2.z * w0[k+2] + b2.w * w0[k+3];
            a21 += b2.x * w1[k] + b2.y * w1[k+1] + b2.z * w1[k+2] + b2.w * w1[k+3];
            a30 += b3.x * w0[k] + b3.y * w0[k+1] + b3.z * w0[k+2] + b3.w * w0[k+3];
            a31 += b3.x * w1[k] + b3.y * w1[k+1] + b3.z * w1[k+2] + b3.w * w1[k+3];
        }

        if (more) sle[buf ^ 1][w][lane >> 4][lane & 15] = qn;

        float d0 = den[s4.x], d1 = den[s4.y], d2 = den[s4.z], d3 = den[s4.w];
        const float g0 = x4.x / d0, g1 = x4.y / d1;
        const float g2 = x4.z / d2, g3 = x4.w / d3;
        const long eb = (long)g * 4;
        *(float2*)(out + (eb + 0) * F_DIM + 2 * lane) = make_float2(g0 * a00, g0 * a01);
        *(float2*)(out + (eb + 1) * F_DIM + 2 * lane) = make_float2(g1 * a10, g1 * a11);
        *(float2*)(out + (eb + 2) * F_DIM + 2 * lane) = make_float2(g2 * a20, g2 * a21);
        *(float2*)(out + (eb + 3) * F_DIM + 2 * lane) = make_float2(g3 * a30, g3 * a31);

        if (!more) break;
        g = gn;
        buf ^= 1;
    }
}

extern "C" void kernel_launch(void* const* d_in, const int* in_sizes, int n_in,
                              void* d_out, int out_size, void* d_ws, size_t ws_size,
                              hipStream_t stream) {
    const float* h     = (const float*)d_in[0];
    const float* el    = (const float*)d_in[1];
    const float* Wfc   = (const float*)d_in[2];
    const float* Wattn = (const float*)d_in[3];
    const int*   src   = (const int*)d_in[4];
    float* out = (float*)d_out;

    int N = in_sizes[0] / N_DIM;   // 50000
    int E = in_sizes[4];           // 800000

    // workspace (floats): [v:64][u:N][den:N][ex:E][den_rep:8N]
    float* v_ws = (float*)d_ws;
    float* u_ws = (float*)d_ws + 64;
    float* den  = (float*)d_ws + 64 + N;
    float* exb  = (float*)d_ws + 64 + 2 * (size_t)N;
    float* drep = (float*)d_ws + 64 + 2 * (size_t)N + E;

    hipMemsetAsync(drep, 0, (size_t)NREP * N * sizeof(float), stream);

    k_u<<<1024, 256, 0, stream>>>(h, Wfc, Wattn, u_ws, v_ws, N);
    k_se<<<1024, 256, 0, stream>>>(el, v_ws, u_ws, src, exb, drep, E, N);
    k_merge<<<(N + 255) / 256, 256, 0, stream>>>(drep, den, N);
    k_out<<<2048, 256, 0, stream>>>(el, Wfc, src, exb, den, out, E);
}